// Round 13
// baseline (344.182 us; speedup 1.0000x reference)
//
#include <hip/hip_runtime.h>
#include <hip/hip_bf16.h>

#define B_ 1024
#define D_ 256
#define R_ 16384
#define W_ 64

typedef float f32x4 __attribute__((ext_vector_type(4)));
typedef __bf16 bf16x8 __attribute__((ext_vector_type(8)));

__device__ __forceinline__ float bf2f(unsigned short u) {
    union { unsigned int i; float f; } v; v.i = ((unsigned int)u) << 16; return v.f;
}
__device__ __forceinline__ unsigned short f2bf(float f) {
    union { float fv; unsigned int i; } v; v.fv = f;
    unsigned int r = v.i + 0x7FFFu + ((v.i >> 16) & 1u);
    return (unsigned short)(r >> 16);
}
__device__ __forceinline__ f32x4 mfma16(bf16x8 a, bf16x8 b, f32x4 c) {
    return __builtin_amdgcn_mfma_f32_16x16x32_bf16(a, b, c, 0, 0, 0);
}
__device__ __forceinline__ bf16x8 ld_bf8(const unsigned short* p) {
    return *(const bf16x8*)p;
}

// ---------------- arena element offsets (each segment start 16-elem aligned) ----
#define AO_X     0
#define AO_WV    262144
#define AO_BV    278528
#define AO_WB    278592
#define AO_BB    278848
#define AO_WG    278864
#define AO_BG    279120
#define AO_WP    279136
#define AO_BP    4473440
#define AO_CK    4489824
#define AO_CB    4489840
#define AO_MEM   4489856
#define AO_TOT   5538432

__global__ __launch_bounds__(256) void k_sentinel(float* __restrict__ out, float val) {
    out[blockIdx.x * 256 + threadIdx.x] = val;
}

__global__ __launch_bounds__(256) void k_zero(float* __restrict__ z) {
    z[blockIdx.x * 256 + threadIdx.x] = 0.f;
}

// ---------------- K-convert: fp32 inputs -> bf16 arena ----------------
__global__ __launch_bounds__(256) void k_convert(
        const float* x, const float* Wv, const float* bv, const float* Wb, const float* bb,
        const float* Wg, const float* bg, const float* Wp, const float* bp,
        const float* ck, const float* cb, const float* mem,
        unsigned short* __restrict__ dst) {
    int base = blockIdx.x * 512 + threadIdx.x;
#pragma unroll
    for (int h = 0; h < 2; h++) {
        int idx = base + h * 256;
        if (idx >= AO_TOT) continue;
        const float* p; int st; int n;
        if      (idx >= AO_MEM) { p = mem; st = AO_MEM; n = R_ * W_; }
        else if (idx >= AO_CB)  { p = cb;  st = AO_CB;  n = 1; }
        else if (idx >= AO_CK)  { p = ck;  st = AO_CK;  n = 3; }
        else if (idx >= AO_BP)  { p = bp;  st = AO_BP;  n = R_; }
        else if (idx >= AO_WP)  { p = Wp;  st = AO_WP;  n = D_ * R_; }
        else if (idx >= AO_BG)  { p = bg;  st = AO_BG;  n = 1; }
        else if (idx >= AO_WG)  { p = Wg;  st = AO_WG;  n = D_; }
        else if (idx >= AO_BB)  { p = bb;  st = AO_BB;  n = 1; }
        else if (idx >= AO_WB)  { p = Wb;  st = AO_WB;  n = D_; }
        else if (idx >= AO_BV)  { p = bv;  st = AO_BV;  n = W_; }
        else if (idx >= AO_WV)  { p = Wv;  st = AO_WV;  n = D_ * W_; }
        else                    { p = x;   st = AO_X;   n = B_ * D_; }
        int local = idx - st;
        dst[idx] = (local < n) ? f2bf(p[local]) : (unsigned short)0;
    }
}

// ---------------- K0: transpose Wp [D,R] -> WpT [R,D] ----------------
__global__ __launch_bounds__(256) void k_transpose_wp(const unsigned short* __restrict__ Wp,
                                                      unsigned short* __restrict__ WpT) {
    __shared__ unsigned short tile[64][66];
    int r0 = blockIdx.x * 64, d0 = blockIdx.y * 64;
    int t = threadIdx.x, lane = t & 63, wv = t >> 6;
#pragma unroll
    for (int i = 0; i < 16; i++) {
        int dl = wv + 4 * i;
        tile[dl][lane] = Wp[(d0 + dl) * R_ + r0 + lane];
    }
    __syncthreads();
#pragma unroll
    for (int i = 0; i < 16; i++) {
        int rl = wv + 4 * i;
        WpT[(r0 + rl) * D_ + d0 + lane] = tile[lane][rl];
    }
}

// ---------------- K1: controller heads: v, vb, bovn=beta/vn, beta, gamma ----------
__global__ __launch_bounds__(64) void k_heads(const unsigned short* __restrict__ x,
        const unsigned short* __restrict__ Wv, const unsigned short* __restrict__ bv,
        const unsigned short* __restrict__ Wb, const unsigned short* __restrict__ bb,
        const unsigned short* __restrict__ Wg, const unsigned short* __restrict__ bg,
        float* __restrict__ v, unsigned short* __restrict__ vb,
        float* __restrict__ bovn, float* __restrict__ beta, float* __restrict__ gamma) {
    __shared__ float sx[256];
    int b = blockIdx.x, lane = threadIdx.x;
#pragma unroll
    for (int j = 0; j < 4; j++) sx[lane + 64 * j] = bf2f(x[b * 256 + lane + 64 * j]);
    __syncthreads();
    float acc = 0.f;
#pragma unroll 8
    for (int d = 0; d < 256; d++) acc += sx[d] * bf2f(Wv[d * 64 + lane]);
    acc += bf2f(bv[lane]);
    v[b * 64 + lane] = acc;
    vb[b * 64 + lane] = f2bf(acc);
    float sq = acc * acc;
#pragma unroll
    for (int d = 32; d >= 1; d >>= 1) sq += __shfl_xor(sq, d, 64);
    float pb = 0.f, pg = 0.f;
#pragma unroll
    for (int j = 0; j < 4; j++) {
        float xv = sx[lane + 64 * j];
        pb += xv * bf2f(Wb[lane + 64 * j]);
        pg += xv * bf2f(Wg[lane + 64 * j]);
    }
#pragma unroll
    for (int d = 32; d >= 1; d >>= 1) { pb += __shfl_xor(pb, d, 64); pg += __shfl_xor(pg, d, 64); }
    if (lane == 0) {
        float vn = sqrtf(sq);
        float zb = pb + bf2f(bb[0]);
        float zg = pg + bf2f(bg[0]);
        float be = (zb > 20.f) ? zb : log1pf(__expf(zb));
        beta[b]  = be;
        bovn[b]  = be / (vn + 1e-16f);
        gamma[b] = 1.f + ((zg > 20.f) ? zg : log1pf(__expf(zg)));
    }
}

// ---------------- K2: mem row inverse norms ----------------
__global__ __launch_bounds__(256) void k_mn(const unsigned short* __restrict__ mem, float* __restrict__ invmn) {
    int lane = threadIdx.x & 63;
    int gw = blockIdx.x * 4 + (threadIdx.x >> 6);
    for (int row = gw; row < R_; row += 256) {
        float m = bf2f(mem[row * 64 + lane]);
        float s = m * m;
#pragma unroll
        for (int d = 32; d >= 1; d >>= 1) s += __shfl_xor(s, d, 64);
        if (lane == 0) invmn[row] = 1.0f / (sqrtf(s) + 1e-16f);
    }
}

// ---------------- K3: sim MFMA -> E = exp(acc*bovn*invmn - beta), S[b] ----------
__global__ __launch_bounds__(256, 8) void k_sim(const unsigned short* __restrict__ vb,
        const unsigned short* __restrict__ mem,
        const float* __restrict__ bovn, const float* __restrict__ invmn,
        const float* __restrict__ beta,
        unsigned short* __restrict__ E, float* __restrict__ S) {
    __shared__ unsigned short etile[64][132];
    __shared__ float sred[4][64];
    int bx = blockIdx.x;
    int rc = bx & 127, tb = bx >> 7;
    int t = threadIdx.x, wv = t >> 6, l = t & 63;
    int lane15 = l & 15, quad = l >> 4;
    int rr0 = rc * 128 + wv * 32 + lane15;
    bf16x8 bm[2][2];
    float im[2];
#pragma unroll
    for (int nt = 0; nt < 2; nt++) {
        int rr = rr0 + nt * 16;
        bm[nt][0] = ld_bf8(mem + rr * 64 + quad * 8);
        bm[nt][1] = ld_bf8(mem + rr * 64 + 32 + quad * 8);
        im[nt] = invmn[rr];
    }
    bf16x8 afr[4][2];
    float bvl[4][4], bel[4][4];
#pragma unroll
    for (int m = 0; m < 4; m++) {
        int brow = tb * 64 + m * 16 + lane15;
        afr[m][0] = ld_bf8(vb + brow * 64 + quad * 8);
        afr[m][1] = ld_bf8(vb + brow * 64 + 32 + quad * 8);
#pragma unroll
        for (int reg = 0; reg < 4; reg++) {
            int b2 = tb * 64 + m * 16 + quad * 4 + reg;
            bvl[m][reg] = bovn[b2];
            bel[m][reg] = beta[b2];
        }
    }
    float sp[4][4];
#pragma unroll
    for (int m = 0; m < 4; m++)
#pragma unroll
        for (int r = 0; r < 4; r++) sp[m][r] = 0.f;

#pragma unroll
    for (int nt = 0; nt < 2; nt++) {
        int rl = wv * 32 + nt * 16 + lane15;
#pragma unroll
        for (int m = 0; m < 4; m++) {
            f32x4 acc = (f32x4){0.f, 0.f, 0.f, 0.f};
            acc = mfma16(afr[m][0], bm[nt][0], acc);
            acc = mfma16(afr[m][1], bm[nt][1], acc);
#pragma unroll
            for (int reg = 0; reg < 4; reg++) {
                float e = __expf(acc[reg] * (bvl[m][reg] * im[nt]) - bel[m][reg]);
                sp[m][reg] += e;
                etile[m * 16 + quad * 4 + reg][rl] = f2bf(e);
            }
        }
    }
#pragma unroll
    for (int m = 0; m < 4; m++)
#pragma unroll
        for (int reg = 0; reg < 4; reg++) {
            float s = sp[m][reg];
            s += __shfl_xor(s, 1, 64); s += __shfl_xor(s, 2, 64);
            s += __shfl_xor(s, 4, 64); s += __shfl_xor(s, 8, 64);
            if (lane15 == 0) sred[wv][m * 16 + quad * 4 + reg] = s;
        }
    __syncthreads();
#pragma unroll
    for (int j = 0; j < 4; j++) {
        int idx8 = t + j * 256;
        int row = idx8 >> 4;
        int c8 = (idx8 & 15) * 8;
        *(bf16x8*)(E + (size_t)(tb * 64 + row) * R_ + rc * 128 + c8) =
            *(const bf16x8*)&etile[row][c8];
    }
    if (t < 64)
        atomicAdd(&S[tb * 64 + t], sred[0][t] + sred[1][t] + sred[2][t] + sred[3][t]);
}

// ---------------- K4: conv+pow -> AT [R,B] (transposed!), T[b] ----------------
__global__ __launch_bounds__(256) void k_conv(const unsigned short* __restrict__ E,
        unsigned short* __restrict__ AT,
        const float* __restrict__ S, const float* __restrict__ gamma,
        const unsigned short* __restrict__ conv_k, const unsigned short* __restrict__ conv_b,
        float* __restrict__ T) {
    __shared__ unsigned short ein[64][132];
    __shared__ unsigned short hl[64], hr[64];
    __shared__ unsigned short aout[128][68];
    __shared__ float red[64], sS[64], sG[64];
    float k0 = bf2f(conv_k[0]), k1 = bf2f(conv_k[1]), k2 = bf2f(conv_k[2]);
    float cb = bf2f(conv_b[0]);
    int b0 = (blockIdx.x >> 7) * 64;
    int r0 = (blockIdx.x & 127) * 128;
    int t = threadIdx.x;
    if (t < 64) {
        red[t] = 0.f;
        sS[t] = 1.0f / S[b0 + t];
        sG[t] = gamma[b0 + t];
        hl[t] = (r0 > 0) ? E[(b0 + t) * R_ + r0 - 1] : (unsigned short)0;
    } else if (t < 128) {
        int tb = t - 64;
        hr[tb] = (r0 + 128 < R_) ? E[(b0 + tb) * R_ + r0 + 128] : (unsigned short)0;
    }
#pragma unroll
    for (int j = 0; j < 8; j++) {
        int idx4 = t + j * 256;
        int row = idx4 >> 5, c4 = (idx4 & 31) * 4;
        *(ushort4*)&ein[row][c4] = *(const ushort4*)(E + (b0 + row) * R_ + r0 + c4);
    }
    __syncthreads();
#pragma unroll 4
    for (int j = 0; j < 32; j++) {
        int idx = t + j * 256;
        int row = idx >> 7, col = idx & 127;
        float el = (col == 0)   ? bf2f(hl[row]) : bf2f(ein[row][col - 1]);
        float ec = bf2f(ein[row][col]);
        float er = (col == 127) ? bf2f(hr[row]) : bf2f(ein[row][col + 1]);
        float wc = (k0 * el + k1 * ec + k2 * er) * sS[row] + cb;
        wc = fmaxf(wc, 1e-30f);
        float au = __expf(sG[row] * __logf(wc));
        aout[col][row] = f2bf(au);
        float s = au;
#pragma unroll
        for (int d = 32; d >= 1; d >>= 1) s += __shfl_xor(s, d, 64);
        if ((t & 63) == 0) atomicAdd(&red[row], s);
    }
    __syncthreads();
    if (t < 64) atomicAdd(&T[b0 + t], red[t]);
#pragma unroll
    for (int j = 0; j < 8; j++) {
        int idx4 = t + j * 256;
        int rrow = idx4 >> 4, c4 = (idx4 & 15) * 4;
        *(ushort4*)(AT + (size_t)(r0 + rrow) * B_ + b0 + c4) = *(ushort4*)&aout[rrow][c4];
    }
}

// ---------------- K4b: build vp' [80,1024] bf16 ----------------
__global__ __launch_bounds__(256) void k_vp2(const float* __restrict__ v, const float* __restrict__ T,
                                             unsigned short* __restrict__ vpb) {
    int idx = blockIdx.x * 256 + threadIdx.x;
    int m = idx >> 10, b = idx & 1023;
    float s = 1.0f / ((T[b] + (float)R_ * 1e-16f) * (float)B_);
    float val = (m < 64) ? v[b * 64 + m] * s : ((m == 64) ? s : 0.f);
    vpb[idx] = f2bf(val);
}

// ---------------- K5: MFMA GEMM mem2T = mem*(1-er) + vp'^ AT ----------------
__global__ __launch_bounds__(256) void k_add(const unsigned short* __restrict__ AT,
        const unsigned short* __restrict__ vpb,
        const unsigned short* __restrict__ memb, unsigned short* __restrict__ mem2T) {
    __shared__ unsigned short smem[64][68];
    __shared__ unsigned short sm2[64][68];
    int r0 = blockIdx.x * 64;
    int t = threadIdx.x, wv = t >> 6, l = t & 63;
    int lane15 = l & 15, quad = l >> 4;
#pragma unroll
    for (int j = 0; j < 4; j++) {
        int idx4 = t + j * 256;
        int rl = idx4 >> 4, w4 = (idx4 & 15) * 4;
        *(ushort4*)&smem[rl][w4] = *(const ushort4*)(memb + (r0 + rl) * 64 + w4);
    }
    __syncthreads();

    const unsigned short* Brow = AT + (size_t)(r0 + wv * 16 + lane15) * B_ + quad * 8;
    const unsigned short* A0 = vpb + (0 * 16 + lane15) * B_ + quad * 8;
    const unsigned short* A1 = vpb + (1 * 16 + lane15) * B_ + quad * 8;
    const unsigned short* A2 = vpb + (2 * 16 + lane15) * B_ + quad * 8;
    const unsigned short* A3 = vpb + (3 * 16 + lane15) * B_ + quad * 8;
    const unsigned short* A4 = vpb + (4 * 16 + lane15) * B_ + quad * 8;
    f32x4 acc0 = {0,0,0,0}, acc1 = {0,0,0,0}, acc2 = {0,0,0,0}, acc3 = {0,0,0,0}, acc4 = {0,0,0,0};
#pragma unroll 4
    for (int k0 = 0; k0 < B_; k0 += 32) {
        bf16x8 bf = ld_bf8(Brow + k0);
        acc0 = mfma16(ld_bf8(A0 + k0), bf, acc0);
        acc1 = mfma16(ld_bf8(A1 + k0), bf, acc1);
        acc2 = mfma16(ld_bf8(A2 + k0), bf, acc2);
        acc3 = mfma16(ld_bf8(A3 + k0), bf, acc3);
        acc4 = mfma16(ld_bf8(A4 + k0), bf, acc4);
    }
    float er = __shfl(acc4[0], l & 15, 64);
    float ome = 1.f - er;
    f32x4 accs[4] = {acc0, acc1, acc2, acc3};
#pragma unroll
    for (int mt = 0; mt < 4; mt++) {
#pragma unroll
        for (int reg = 0; reg < 4; reg++) {
            int w = mt * 16 + quad * 4 + reg;
            int rl = wv * 16 + lane15;
            float m2 = bf2f(smem[rl][w]) * ome + accs[mt][reg];
            sm2[w][rl] = f2bf(m2);
        }
    }
    __syncthreads();
#pragma unroll
    for (int j = 0; j < 4; j++) {
        int idx4 = t + j * 256;
        int w = idx4 >> 4, r4 = (idx4 & 15) * 4;
        *(ushort4*)(mem2T + (size_t)w * R_ + r0 + r4) = *(ushort4*)&sm2[w][r4];
    }
}

// ---------------- K6: flash read head v5 — 2 m-tiles/wave, 128 r/block --------
// 1024 blocks: rc = bx&127 (128 r), tg = bx>>7 (128 b). 4 staging phases of 32 r;
// PV per 64-r half. LDS: bstage 32x264 (16,896 B) + etile 128x68 (17,408 B)
// = 34,304 B -> 4 blocks/CU capacity; grid gives 4 blocks/CU.
__global__ __launch_bounds__(256, 4) void k_read(const unsigned short* __restrict__ x,
        const unsigned short* __restrict__ WpT, const unsigned short* __restrict__ bp,
        const unsigned short* __restrict__ mem2T,
        float* __restrict__ outacc, float* __restrict__ Sp) {
    __shared__ unsigned short bstage[32 * 264];
    __shared__ unsigned short etile[128][68];
    int bx = blockIdx.x;
    int rc = bx & 127, tg = bx >> 7;
    int t = threadIdx.x, wv = t >> 6, l = t & 63;
    int lane15 = l & 15, quad = l >> 4;
    bf16x8 afr[2][8];
#pragma unroll
    for (int m2 = 0; m2 < 2; m2++) {
        int brow = tg * 128 + (wv + 4 * m2) * 16 + lane15;
#pragma unroll
        for (int kk = 0; kk < 8; kk++)
            afr[m2][kk] = ld_bf8(x + brow * 256 + kk * 32 + quad * 8);
    }
    f32x4 accO[2][4];
#pragma unroll
    for (int m2 = 0; m2 < 2; m2++)
#pragma unroll
        for (int nt = 0; nt < 4; nt++) accO[m2][nt] = (f32x4){0.f, 0.f, 0.f, 0.f};
    float sp[2][4] = {{0.f, 0.f, 0.f, 0.f}, {0.f, 0.f, 0.f, 0.f}};

    for (int half = 0; half < 2; half++) {
        for (int ch = 0; ch < 2; ch++) {
            int rbase = rc * 128 + half * 64 + ch * 32;
            {   // cooperative stage: WpT rows [rbase, rbase+32) x 256 into LDS
                int row = t >> 3, cg = (t & 7) * 8;
                const unsigned short* src = WpT + (size_t)(rbase + row) * 256 + cg;
                unsigned short* dst = bstage + row * 264 + cg;
#pragma unroll
                for (int j = 0; j < 4; j++)
                    *(bf16x8*)(dst + 64 * j) = *(const bf16x8*)(src + 64 * j);
            }
            __syncthreads();
#pragma unroll
            for (int nt = 0; nt < 2; nt++) {
                f32x4 a0 = (f32x4){0.f, 0.f, 0.f, 0.f};
                f32x4 a1 = (f32x4){0.f, 0.f, 0.f, 0.f};
                const unsigned short* bb = bstage + (nt * 16 + lane15) * 264 + quad * 8;
#pragma unroll
                for (int kk = 0; kk < 8; kk++) {
                    bf16x8 bfr = *(const bf16x8*)(bb + kk * 32);
                    a0 = mfma16(afr[0][kk], bfr, a0);
                    a1 = mfma16(afr[1][kk], bfr, a1);
                }
                int rr = rbase + nt * 16 + lane15;
                float bpv = bf2f(bp[rr]);
                int rloc = ch * 32 + nt * 16 + lane15;   // 0..63 within half
#pragma unroll
                for (int reg = 0; reg < 4; reg++) {
                    float e0 = __expf(a0[reg] + bpv);
                    unsigned short u0 = f2bf(e0);
                    sp[0][reg] += bf2f(u0);
                    etile[wv * 16 + quad * 4 + reg][rloc] = u0;
                    float e1 = __expf(a1[reg] + bpv);
                    unsigned short u1 = f2bf(e1);
                    sp[1][reg] += bf2f(u1);
                    etile[64 + wv * 16 + quad * 4 + reg][rloc] = u1;
                }
            }
            __syncthreads();
        }
        // PV over this half's 64 r (etile rows wave-private; no barrier needed)
#pragma unroll
        for (int m2 = 0; m2 < 2; m2++) {
            const unsigned short* abase = &etile[m2 * 64 + wv * 16 + lane15][quad * 8];
#pragma unroll
            for (int nt = 0; nt < 4; nt++) {
                const unsigned short* vbase = mem2T + (size_t)(nt * 16 + lane15) * R_
                                              + rc * 128 + half * 64 + quad * 8;
#pragma unroll
                for (int kk = 0; kk < 2; kk++) {
                    bf16x8 ea = *(const bf16x8*)(abase + kk * 32);
                    bf16x8 vv = *(const bf16x8*)(vbase + kk * 32);
                    accO[m2][nt] = mfma16(ea, vv, accO[m2][nt]);
                }
            }
        }
    }
#pragma unroll
    for (int m2 = 0; m2 < 2; m2++) {
#pragma unroll
        for (int nt = 0; nt < 4; nt++) {
            int wcol = nt * 16 + lane15;
#pragma unroll
            for (int reg = 0; reg < 4; reg++) {
                int b2 = tg * 128 + (wv + 4 * m2) * 16 + quad * 4 + reg;
                atomicAdd(&outacc[b2 * 64 + wcol], accO[m2][nt][reg]);
            }
        }
#pragma unroll
        for (int reg = 0; reg < 4; reg++) {
            float s = sp[m2][reg];
            s += __shfl_xor(s, 1, 64); s += __shfl_xor(s, 2, 64);
            s += __shfl_xor(s, 4, 64); s += __shfl_xor(s, 8, 64);
            if (lane15 == 0) {
                int b2 = tg * 128 + (wv + 4 * m2) * 16 + quad * 4 + reg;
                atomicAdd(&Sp[b2], s);
            }
        }
    }
}

// ---------------- K7: out = outacc / Sp -> FP32 ----------------
__global__ __launch_bounds__(256) void k_out(const float* __restrict__ outacc,
                                             const float* __restrict__ Sp,
                                             float* __restrict__ out) {
    int idx = blockIdx.x * 256 + threadIdx.x;
    int b = idx >> 6;
    out[idx] = outacc[idx] / Sp[b];
}

extern "C" void kernel_launch(void* const* d_in, const int* in_sizes, int n_in,
                              void* d_out, int out_size, void* d_ws, size_t ws_size,
                              hipStream_t stream) {
    (void)n_in; (void)out_size;
    float* outp = (float*)d_out;

    char* ws = (char*)d_ws;
    size_t o = 0;
    unsigned short* arena = (unsigned short*)(ws + o); o += (size_t)AO_TOT * 2;
    unsigned short* WpT = (unsigned short*)(ws + o); o += (size_t)R_ * D_ * 2;
    unsigned short* E   = (unsigned short*)(ws + o); o += (size_t)B_ * R_ * 2;
    unsigned short* AT  = (unsigned short*)(ws + o); o += (size_t)B_ * R_ * 2;
    float* v            = (float*)(ws + o);          o += (size_t)B_ * 64 * 4;
    unsigned short* vb  = (unsigned short*)(ws + o); o += (size_t)B_ * 64 * 2;
    unsigned short* vpb = (unsigned short*)(ws + o); o += (size_t)80 * B_ * 2;
    float* invmn        = (float*)(ws + o);          o += (size_t)R_ * 4;
    float* bovn         = (float*)(ws + o);          o += 4096;
    float* beta         = (float*)(ws + o);          o += 4096;
    float* gamma        = (float*)(ws + o);          o += 4096;
    unsigned short* m2T = (unsigned short*)(ws + o); o += (size_t)R_ * 64 * 2;
    float* zbase  = (float*)(ws + o);
    float* S      = (float*)(ws + o);                o += 4096;
    float* T      = (float*)(ws + o);                o += 4096;
    float* Sp     = (float*)(ws + o);                o += 4096;
    float* outacc = (float*)(ws + o);                o += (size_t)B_ * 64 * 4;

    if (ws_size < o) {
        k_sentinel<<<256, 256, 0, stream>>>(outp, 1000.0f);
        return;
    }
    if (in_sizes[0] != B_ * D_ || in_sizes[7] != D_ * R_ || in_sizes[11] != R_ * W_) {
        k_sentinel<<<256, 256, 0, stream>>>(outp, 2000.0f);
        return;
    }

    k_zero<<<268, 256, 0, stream>>>(zbase);
    k_convert<<<(AO_TOT + 511) / 512, 256, 0, stream>>>(
        (const float*)d_in[0], (const float*)d_in[1], (const float*)d_in[2],
        (const float*)d_in[3], (const float*)d_in[4], (const float*)d_in[5],
        (const float*)d_in[6], (const float*)d_in[7], (const float*)d_in[8],
        (const float*)d_in[9], (const float*)d_in[10], (const float*)d_in[11], arena);

    k_transpose_wp<<<dim3(256, 4), 256, 0, stream>>>(arena + AO_WP, WpT);
    k_heads<<<1024, 64, 0, stream>>>(arena + AO_X, arena + AO_WV, arena + AO_BV,
                                     arena + AO_WB, arena + AO_BB, arena + AO_WG,
                                     arena + AO_BG, v, vb, bovn, beta, gamma);
    k_mn<<<64, 256, 0, stream>>>(arena + AO_MEM, invmn);
    k_sim<<<2048, 256, 0, stream>>>(vb, arena + AO_MEM, bovn, invmn, beta, E, S);
    k_conv<<<2048, 256, 0, stream>>>(E, AT, S, gamma, arena + AO_CK, arena + AO_CB, T);
    k_vp2<<<320, 256, 0, stream>>>(v, T, vpb);
    k_add<<<256, 256, 0, stream>>>(AT, vpb, arena + AO_MEM, m2T);
    k_read<<<1024, 256, 0, stream>>>(arena + AO_X, WpT, arena + AO_BP, m2T, outacc, Sp);
    k_out<<<256, 256, 0, stream>>>(outacc, Sp, outp);
}

// Round 14
// 294.376 us; speedup vs baseline: 1.1692x; 1.1692x over previous
//
#include <hip/hip_runtime.h>
#include <hip/hip_bf16.h>

#define B_ 1024
#define D_ 256
#define R_ 16384
#define W_ 64

typedef float f32x4 __attribute__((ext_vector_type(4)));
typedef __bf16 bf16x8 __attribute__((ext_vector_type(8)));

__device__ __forceinline__ float bf2f(unsigned short u) {
    union { unsigned int i; float f; } v; v.i = ((unsigned int)u) << 16; return v.f;
}
__device__ __forceinline__ unsigned short f2bf(float f) {
    union { float fv; unsigned int i; } v; v.fv = f;
    unsigned int r = v.i + 0x7FFFu + ((v.i >> 16) & 1u);
    return (unsigned short)(r >> 16);
}
__device__ __forceinline__ f32x4 mfma16(bf16x8 a, bf16x8 b, f32x4 c) {
    return __builtin_amdgcn_mfma_f32_16x16x32_bf16(a, b, c, 0, 0, 0);
}
__device__ __forceinline__ bf16x8 ld_bf8(const unsigned short* p) {
    return *(const bf16x8*)p;
}

// ---------------- arena element offsets (each segment start 16-elem aligned) ----
#define AO_X     0
#define AO_WV    262144
#define AO_BV    278528
#define AO_WB    278592
#define AO_BB    278848
#define AO_WG    278864
#define AO_BG    279120
#define AO_WP    279136
#define AO_BP    4473440
#define AO_CK    4489824
#define AO_CB    4489840
#define AO_MEM   4489856
#define AO_TOT   5538432

__global__ __launch_bounds__(256) void k_sentinel(float* __restrict__ out, float val) {
    out[blockIdx.x * 256 + threadIdx.x] = val;
}

__global__ __launch_bounds__(256) void k_zero(float* __restrict__ z) {
    z[blockIdx.x * 256 + threadIdx.x] = 0.f;
}

// ---------------- K-convert: fp32 inputs -> bf16 arena ----------------
__global__ __launch_bounds__(256) void k_convert(
        const float* x, const float* Wv, const float* bv, const float* Wb, const float* bb,
        const float* Wg, const float* bg, const float* Wp, const float* bp,
        const float* ck, const float* cb, const float* mem,
        unsigned short* __restrict__ dst) {
    int base = blockIdx.x * 512 + threadIdx.x;
#pragma unroll
    for (int h = 0; h < 2; h++) {
        int idx = base + h * 256;
        if (idx >= AO_TOT) continue;
        const float* p; int st; int n;
        if      (idx >= AO_MEM) { p = mem; st = AO_MEM; n = R_ * W_; }
        else if (idx >= AO_CB)  { p = cb;  st = AO_CB;  n = 1; }
        else if (idx >= AO_CK)  { p = ck;  st = AO_CK;  n = 3; }
        else if (idx >= AO_BP)  { p = bp;  st = AO_BP;  n = R_; }
        else if (idx >= AO_WP)  { p = Wp;  st = AO_WP;  n = D_ * R_; }
        else if (idx >= AO_BG)  { p = bg;  st = AO_BG;  n = 1; }
        else if (idx >= AO_WG)  { p = Wg;  st = AO_WG;  n = D_; }
        else if (idx >= AO_BB)  { p = bb;  st = AO_BB;  n = 1; }
        else if (idx >= AO_WB)  { p = Wb;  st = AO_WB;  n = D_; }
        else if (idx >= AO_BV)  { p = bv;  st = AO_BV;  n = W_; }
        else if (idx >= AO_WV)  { p = Wv;  st = AO_WV;  n = D_ * W_; }
        else                    { p = x;   st = AO_X;   n = B_ * D_; }
        int local = idx - st;
        dst[idx] = (local < n) ? f2bf(p[local]) : (unsigned short)0;
    }
}

// ---------------- K0: transpose Wp [D,R] -> WpT [R,D] ----------------
__global__ __launch_bounds__(256) void k_transpose_wp(const unsigned short* __restrict__ Wp,
                                                      unsigned short* __restrict__ WpT) {
    __shared__ unsigned short tile[64][66];
    int r0 = blockIdx.x * 64, d0 = blockIdx.y * 64;
    int t = threadIdx.x, lane = t & 63, wv = t >> 6;
#pragma unroll
    for (int i = 0; i < 16; i++) {
        int dl = wv + 4 * i;
        tile[dl][lane] = Wp[(d0 + dl) * R_ + r0 + lane];
    }
    __syncthreads();
#pragma unroll
    for (int i = 0; i < 16; i++) {
        int rl = wv + 4 * i;
        WpT[(r0 + rl) * D_ + d0 + lane] = tile[lane][rl];
    }
}

// ---------------- K1: controller heads: v, vb, bovn=beta/vn, beta, gamma ----------
__global__ __launch_bounds__(64) void k_heads(const unsigned short* __restrict__ x,
        const unsigned short* __restrict__ Wv, const unsigned short* __restrict__ bv,
        const unsigned short* __restrict__ Wb, const unsigned short* __restrict__ bb,
        const unsigned short* __restrict__ Wg, const unsigned short* __restrict__ bg,
        float* __restrict__ v, unsigned short* __restrict__ vb,
        float* __restrict__ bovn, float* __restrict__ beta, float* __restrict__ gamma) {
    __shared__ float sx[256];
    int b = blockIdx.x, lane = threadIdx.x;
#pragma unroll
    for (int j = 0; j < 4; j++) sx[lane + 64 * j] = bf2f(x[b * 256 + lane + 64 * j]);
    __syncthreads();
    float acc = 0.f;
#pragma unroll 8
    for (int d = 0; d < 256; d++) acc += sx[d] * bf2f(Wv[d * 64 + lane]);
    acc += bf2f(bv[lane]);
    v[b * 64 + lane] = acc;
    vb[b * 64 + lane] = f2bf(acc);
    float sq = acc * acc;
#pragma unroll
    for (int d = 32; d >= 1; d >>= 1) sq += __shfl_xor(sq, d, 64);
    float pb = 0.f, pg = 0.f;
#pragma unroll
    for (int j = 0; j < 4; j++) {
        float xv = sx[lane + 64 * j];
        pb += xv * bf2f(Wb[lane + 64 * j]);
        pg += xv * bf2f(Wg[lane + 64 * j]);
    }
#pragma unroll
    for (int d = 32; d >= 1; d >>= 1) { pb += __shfl_xor(pb, d, 64); pg += __shfl_xor(pg, d, 64); }
    if (lane == 0) {
        float vn = sqrtf(sq);
        float zb = pb + bf2f(bb[0]);
        float zg = pg + bf2f(bg[0]);
        float be = (zb > 20.f) ? zb : log1pf(__expf(zb));
        beta[b]  = be;
        bovn[b]  = be / (vn + 1e-16f);
        gamma[b] = 1.f + ((zg > 20.f) ? zg : log1pf(__expf(zg)));
    }
}

// ---------------- K2: mem row inverse norms ----------------
__global__ __launch_bounds__(256) void k_mn(const unsigned short* __restrict__ mem, float* __restrict__ invmn) {
    int lane = threadIdx.x & 63;
    int gw = blockIdx.x * 4 + (threadIdx.x >> 6);
    for (int row = gw; row < R_; row += 256) {
        float m = bf2f(mem[row * 64 + lane]);
        float s = m * m;
#pragma unroll
        for (int d = 32; d >= 1; d >>= 1) s += __shfl_xor(s, d, 64);
        if (lane == 0) invmn[row] = 1.0f / (sqrtf(s) + 1e-16f);
    }
}

// ---------------- K3: sim MFMA -> E = exp(acc*bovn*invmn - beta), S[b] ----------
__global__ __launch_bounds__(256, 8) void k_sim(const unsigned short* __restrict__ vb,
        const unsigned short* __restrict__ mem,
        const float* __restrict__ bovn, const float* __restrict__ invmn,
        const float* __restrict__ beta,
        unsigned short* __restrict__ E, float* __restrict__ S) {
    __shared__ unsigned short etile[64][132];
    __shared__ float sred[4][64];
    int bx = blockIdx.x;
    int rc = bx & 127, tb = bx >> 7;
    int t = threadIdx.x, wv = t >> 6, l = t & 63;
    int lane15 = l & 15, quad = l >> 4;
    int rr0 = rc * 128 + wv * 32 + lane15;
    bf16x8 bm[2][2];
    float im[2];
#pragma unroll
    for (int nt = 0; nt < 2; nt++) {
        int rr = rr0 + nt * 16;
        bm[nt][0] = ld_bf8(mem + rr * 64 + quad * 8);
        bm[nt][1] = ld_bf8(mem + rr * 64 + 32 + quad * 8);
        im[nt] = invmn[rr];
    }
    bf16x8 afr[4][2];
    float bvl[4][4], bel[4][4];
#pragma unroll
    for (int m = 0; m < 4; m++) {
        int brow = tb * 64 + m * 16 + lane15;
        afr[m][0] = ld_bf8(vb + brow * 64 + quad * 8);
        afr[m][1] = ld_bf8(vb + brow * 64 + 32 + quad * 8);
#pragma unroll
        for (int reg = 0; reg < 4; reg++) {
            int b2 = tb * 64 + m * 16 + quad * 4 + reg;
            bvl[m][reg] = bovn[b2];
            bel[m][reg] = beta[b2];
        }
    }
    float sp[4][4];
#pragma unroll
    for (int m = 0; m < 4; m++)
#pragma unroll
        for (int r = 0; r < 4; r++) sp[m][r] = 0.f;

#pragma unroll
    for (int nt = 0; nt < 2; nt++) {
        int rl = wv * 32 + nt * 16 + lane15;
#pragma unroll
        for (int m = 0; m < 4; m++) {
            f32x4 acc = (f32x4){0.f, 0.f, 0.f, 0.f};
            acc = mfma16(afr[m][0], bm[nt][0], acc);
            acc = mfma16(afr[m][1], bm[nt][1], acc);
#pragma unroll
            for (int reg = 0; reg < 4; reg++) {
                float e = __expf(acc[reg] * (bvl[m][reg] * im[nt]) - bel[m][reg]);
                sp[m][reg] += e;
                etile[m * 16 + quad * 4 + reg][rl] = f2bf(e);
            }
        }
    }
#pragma unroll
    for (int m = 0; m < 4; m++)
#pragma unroll
        for (int reg = 0; reg < 4; reg++) {
            float s = sp[m][reg];
            s += __shfl_xor(s, 1, 64); s += __shfl_xor(s, 2, 64);
            s += __shfl_xor(s, 4, 64); s += __shfl_xor(s, 8, 64);
            if (lane15 == 0) sred[wv][m * 16 + quad * 4 + reg] = s;
        }
    __syncthreads();
#pragma unroll
    for (int j = 0; j < 4; j++) {
        int idx8 = t + j * 256;
        int row = idx8 >> 4;
        int c8 = (idx8 & 15) * 8;
        *(bf16x8*)(E + (size_t)(tb * 64 + row) * R_ + rc * 128 + c8) =
            *(const bf16x8*)&etile[row][c8];
    }
    if (t < 64)
        atomicAdd(&S[tb * 64 + t], sred[0][t] + sred[1][t] + sred[2][t] + sred[3][t]);
}

// ---------------- K4: conv+pow -> AT [R,B] (transposed!), T[b] ----------------
__global__ __launch_bounds__(256) void k_conv(const unsigned short* __restrict__ E,
        unsigned short* __restrict__ AT,
        const float* __restrict__ S, const float* __restrict__ gamma,
        const unsigned short* __restrict__ conv_k, const unsigned short* __restrict__ conv_b,
        float* __restrict__ T) {
    __shared__ unsigned short ein[64][132];
    __shared__ unsigned short hl[64], hr[64];
    __shared__ unsigned short aout[128][68];
    __shared__ float red[64], sS[64], sG[64];
    float k0 = bf2f(conv_k[0]), k1 = bf2f(conv_k[1]), k2 = bf2f(conv_k[2]);
    float cb = bf2f(conv_b[0]);
    int b0 = (blockIdx.x >> 7) * 64;
    int r0 = (blockIdx.x & 127) * 128;
    int t = threadIdx.x;
    if (t < 64) {
        red[t] = 0.f;
        sS[t] = 1.0f / S[b0 + t];
        sG[t] = gamma[b0 + t];
        hl[t] = (r0 > 0) ? E[(b0 + t) * R_ + r0 - 1] : (unsigned short)0;
    } else if (t < 128) {
        int tb = t - 64;
        hr[tb] = (r0 + 128 < R_) ? E[(b0 + tb) * R_ + r0 + 128] : (unsigned short)0;
    }
#pragma unroll
    for (int j = 0; j < 8; j++) {
        int idx4 = t + j * 256;
        int row = idx4 >> 5, c4 = (idx4 & 31) * 4;
        *(ushort4*)&ein[row][c4] = *(const ushort4*)(E + (b0 + row) * R_ + r0 + c4);
    }
    __syncthreads();
#pragma unroll 4
    for (int j = 0; j < 32; j++) {
        int idx = t + j * 256;
        int row = idx >> 7, col = idx & 127;
        float el = (col == 0)   ? bf2f(hl[row]) : bf2f(ein[row][col - 1]);
        float ec = bf2f(ein[row][col]);
        float er = (col == 127) ? bf2f(hr[row]) : bf2f(ein[row][col + 1]);
        float wc = (k0 * el + k1 * ec + k2 * er) * sS[row] + cb;
        wc = fmaxf(wc, 1e-30f);
        float au = __expf(sG[row] * __logf(wc));
        aout[col][row] = f2bf(au);
        float s = au;
#pragma unroll
        for (int d = 32; d >= 1; d >>= 1) s += __shfl_xor(s, d, 64);
        if ((t & 63) == 0) atomicAdd(&red[row], s);
    }
    __syncthreads();
    if (t < 64) atomicAdd(&T[b0 + t], red[t]);
#pragma unroll
    for (int j = 0; j < 8; j++) {
        int idx4 = t + j * 256;
        int rrow = idx4 >> 4, c4 = (idx4 & 15) * 4;
        *(ushort4*)(AT + (size_t)(r0 + rrow) * B_ + b0 + c4) = *(ushort4*)&aout[rrow][c4];
    }
}

// ---------------- K4b: build vp' [80,1024] bf16 ----------------
__global__ __launch_bounds__(256) void k_vp2(const float* __restrict__ v, const float* __restrict__ T,
                                             unsigned short* __restrict__ vpb) {
    int idx = blockIdx.x * 256 + threadIdx.x;
    int m = idx >> 10, b = idx & 1023;
    float s = 1.0f / ((T[b] + (float)R_ * 1e-16f) * (float)B_);
    float val = (m < 64) ? v[b * 64 + m] * s : ((m == 64) ? s : 0.f);
    vpb[idx] = f2bf(val);
}

// ---------------- K5: MFMA GEMM mem2T = mem*(1-er) + vp'^ AT ----------------
__global__ __launch_bounds__(256) void k_add(const unsigned short* __restrict__ AT,
        const unsigned short* __restrict__ vpb,
        const unsigned short* __restrict__ memb, unsigned short* __restrict__ mem2T) {
    __shared__ unsigned short smem[64][68];
    __shared__ unsigned short sm2[64][68];
    int r0 = blockIdx.x * 64;
    int t = threadIdx.x, wv = t >> 6, l = t & 63;
    int lane15 = l & 15, quad = l >> 4;
#pragma unroll
    for (int j = 0; j < 4; j++) {
        int idx4 = t + j * 256;
        int rl = idx4 >> 4, w4 = (idx4 & 15) * 4;
        *(ushort4*)&smem[rl][w4] = *(const ushort4*)(memb + (r0 + rl) * 64 + w4);
    }
    __syncthreads();

    const unsigned short* Brow = AT + (size_t)(r0 + wv * 16 + lane15) * B_ + quad * 8;
    const unsigned short* A0 = vpb + (0 * 16 + lane15) * B_ + quad * 8;
    const unsigned short* A1 = vpb + (1 * 16 + lane15) * B_ + quad * 8;
    const unsigned short* A2 = vpb + (2 * 16 + lane15) * B_ + quad * 8;
    const unsigned short* A3 = vpb + (3 * 16 + lane15) * B_ + quad * 8;
    const unsigned short* A4 = vpb + (4 * 16 + lane15) * B_ + quad * 8;
    f32x4 acc0 = {0,0,0,0}, acc1 = {0,0,0,0}, acc2 = {0,0,0,0}, acc3 = {0,0,0,0}, acc4 = {0,0,0,0};
#pragma unroll 4
    for (int k0 = 0; k0 < B_; k0 += 32) {
        bf16x8 bf = ld_bf8(Brow + k0);
        acc0 = mfma16(ld_bf8(A0 + k0), bf, acc0);
        acc1 = mfma16(ld_bf8(A1 + k0), bf, acc1);
        acc2 = mfma16(ld_bf8(A2 + k0), bf, acc2);
        acc3 = mfma16(ld_bf8(A3 + k0), bf, acc3);
        acc4 = mfma16(ld_bf8(A4 + k0), bf, acc4);
    }
    float er = __shfl(acc4[0], l & 15, 64);
    float ome = 1.f - er;
    f32x4 accs[4] = {acc0, acc1, acc2, acc3};
#pragma unroll
    for (int mt = 0; mt < 4; mt++) {
#pragma unroll
        for (int reg = 0; reg < 4; reg++) {
            int w = mt * 16 + quad * 4 + reg;
            int rl = wv * 16 + lane15;
            float m2 = bf2f(smem[rl][w]) * ome + accs[mt][reg];
            sm2[w][rl] = f2bf(m2);
        }
    }
    __syncthreads();
#pragma unroll
    for (int j = 0; j < 4; j++) {
        int idx4 = t + j * 256;
        int w = idx4 >> 4, r4 = (idx4 & 15) * 4;
        *(ushort4*)(mem2T + (size_t)w * R_ + r0 + r4) = *(ushort4*)&sm2[w][r4];
    }
}

// ---------------- K6: flash read head (R9 structure + L2-friendly order + prefetch)
// 1024 blocks: tb = bx&15 (16 consecutive blocks share one WpT slice -> L2 reuse),
// rc = bx>>4 (256 r). LDS: bstage 32x264 + etile 64x264 = 50,688 B.
// Staging loads register-double-buffered: phase ss+1's loads issued during phase ss.
__global__ __launch_bounds__(256) void k_read(const unsigned short* __restrict__ x,
        const unsigned short* __restrict__ WpT, const unsigned short* __restrict__ bp,
        const unsigned short* __restrict__ mem2T,
        float* __restrict__ outacc, float* __restrict__ Sp) {
    __shared__ unsigned short bstage[32 * 264];
    __shared__ unsigned short etile[64 * 264];
    int bx = blockIdx.x;
    int tb = bx & 15, rc = bx >> 4;
    int t = threadIdx.x, wv = t >> 6, l = t & 63;
    int lane15 = l & 15, quad = l >> 4;
    int brow = tb * 64 + wv * 16 + lane15;
    bf16x8 afr[8];
#pragma unroll
    for (int kk = 0; kk < 8; kk++)
        afr[kk] = ld_bf8(x + brow * 256 + kk * 32 + quad * 8);
    f32x4 accO[4];
#pragma unroll
    for (int nt = 0; nt < 4; nt++) accO[nt] = (f32x4){0.f, 0.f, 0.f, 0.f};
    float sp[4] = {0.f, 0.f, 0.f, 0.f};

    int srow = t >> 3, scg = (t & 7) * 8;
    bf16x8 pf[4];
    {   // prefetch phase 0
        const unsigned short* src = WpT + (size_t)(rc * 256 + srow) * 256 + scg;
#pragma unroll
        for (int j = 0; j < 4; j++) pf[j] = *(const bf16x8*)(src + 64 * j);
    }
    for (int ss = 0; ss < 8; ss++) {
        {   // commit prefetched rows to LDS, then issue next phase's loads
            unsigned short* dst = bstage + srow * 264 + scg;
#pragma unroll
            for (int j = 0; j < 4; j++) *(bf16x8*)(dst + 64 * j) = pf[j];
        }
        if (ss < 7) {
            const unsigned short* src = WpT
                + (size_t)(rc * 256 + (ss + 1) * 32 + srow) * 256 + scg;
#pragma unroll
            for (int j = 0; j < 4; j++) pf[j] = *(const bf16x8*)(src + 64 * j);
        }
        __syncthreads();
        int rbase = rc * 256 + ss * 32;
#pragma unroll
        for (int nt = 0; nt < 2; nt++) {
            f32x4 acc = (f32x4){0.f, 0.f, 0.f, 0.f};
            const unsigned short* bb = bstage + (nt * 16 + lane15) * 264 + quad * 8;
#pragma unroll
            for (int kk = 0; kk < 8; kk++) {
                bf16x8 bfr = *(const bf16x8*)(bb + kk * 32);
                acc = mfma16(afr[kk], bfr, acc);
            }
            int rr = rbase + nt * 16 + lane15;
            float bpv = bf2f(bp[rr]);
            int rloc = ss * 32 + nt * 16 + lane15;
#pragma unroll
            for (int reg = 0; reg < 4; reg++) {
                float e = __expf(acc[reg] + bpv);
                unsigned short ue = f2bf(e);
                sp[reg] += bf2f(ue);   // match PV numerator quantization
                etile[(wv * 16 + quad * 4 + reg) * 264 + rloc] = ue;
            }
        }
        __syncthreads();
    }
#pragma unroll
    for (int nt = 0; nt < 4; nt++) {
        const unsigned short* vbase = mem2T + (size_t)(nt * 16 + lane15) * R_
                                      + rc * 256 + quad * 8;
        const unsigned short* abase = etile + (wv * 16 + lane15) * 264 + quad * 8;
#pragma unroll
        for (int kk = 0; kk < 8; kk++) {
            bf16x8 ea = *(const bf16x8*)(abase + kk * 32);
            bf16x8 vv = *(const bf16x8*)(vbase + kk * 32);
            accO[nt] = mfma16(ea, vv, accO[nt]);
        }
    }
#pragma unroll
    for (int nt = 0; nt < 4; nt++) {
        int wcol = nt * 16 + lane15;
#pragma unroll
        for (int reg = 0; reg < 4; reg++) {
            int b2 = tb * 64 + wv * 16 + quad * 4 + reg;
            atomicAdd(&outacc[b2 * 64 + wcol], accO[nt][reg]);
        }
    }
#pragma unroll
    for (int reg = 0; reg < 4; reg++) {
        float s = sp[reg];
        s += __shfl_xor(s, 1, 64); s += __shfl_xor(s, 2, 64);
        s += __shfl_xor(s, 4, 64); s += __shfl_xor(s, 8, 64);
        if (lane15 == 0) {
            int b2 = tb * 64 + wv * 16 + quad * 4 + reg;
            atomicAdd(&Sp[b2], s);
        }
    }
}

// ---------------- K7: out = outacc / Sp -> FP32 ----------------
__global__ __launch_bounds__(256) void k_out(const float* __restrict__ outacc,
                                             const float* __restrict__ Sp,
                                             float* __restrict__ out) {
    int idx = blockIdx.x * 256 + threadIdx.x;
    int b = idx >> 6;
    out[idx] = outacc[idx] / Sp[b];
}

extern "C" void kernel_launch(void* const* d_in, const int* in_sizes, int n_in,
                              void* d_out, int out_size, void* d_ws, size_t ws_size,
                              hipStream_t stream) {
    (void)n_in; (void)out_size;
    float* outp = (float*)d_out;

    char* ws = (char*)d_ws;
    size_t o = 0;
    unsigned short* arena = (unsigned short*)(ws + o); o += (size_t)AO_TOT * 2;
    unsigned short* WpT = (unsigned short*)(ws + o); o += (size_t)R_ * D_ * 2;
    unsigned short* E   = (unsigned short*)(ws + o); o += (size_t)B_ * R_ * 2;
    unsigned short* AT  = (unsigned short*)(ws + o); o += (size_t)B_ * R_ * 2;
    float* v            = (float*)(ws + o);          o += (size_t)B_ * 64 * 4;
    unsigned short* vb  = (unsigned short*)(ws + o); o += (size_t)B_ * 64 * 2;
    unsigned short* vpb = (unsigned short*)(ws + o); o += (size_t)80 * B_ * 2;
    float* invmn        = (float*)(ws + o);          o += (size_t)R_ * 4;
    float* bovn         = (float*)(ws + o);          o += 4096;
    float* beta         = (float*)(ws + o);          o += 4096;
    float* gamma        = (float*)(ws + o);          o += 4096;
    unsigned short* m2T = (unsigned short*)(ws + o); o += (size_t)R_ * 64 * 2;
    float* zbase  = (float*)(ws + o);
    float* S      = (float*)(ws + o);                o += 4096;
    float* T      = (float*)(ws + o);                o += 4096;
    float* Sp     = (float*)(ws + o);                o += 4096;
    float* outacc = (float*)(ws + o);                o += (size_t)B_ * 64 * 4;

    if (ws_size < o) {
        k_sentinel<<<256, 256, 0, stream>>>(outp, 1000.0f);
        return;
    }
    if (in_sizes[0] != B_ * D_ || in_sizes[7] != D_ * R_ || in_sizes[11] != R_ * W_) {
        k_sentinel<<<256, 256, 0, stream>>>(outp, 2000.0f);
        return;
    }

    k_zero<<<268, 256, 0, stream>>>(zbase);
    k_convert<<<(AO_TOT + 511) / 512, 256, 0, stream>>>(
        (const float*)d_in[0], (const float*)d_in[1], (const float*)d_in[2],
        (const float*)d_in[3], (const float*)d_in[4], (const float*)d_in[5],
        (const float*)d_in[6], (const float*)d_in[7], (const float*)d_in[8],
        (const float*)d_in[9], (const float*)d_in[10], (const float*)d_in[11], arena);

    k_transpose_wp<<<dim3(256, 4), 256, 0, stream>>>(arena + AO_WP, WpT);
    k_heads<<<1024, 64, 0, stream>>>(arena + AO_X, arena + AO_WV, arena + AO_BV,
                                     arena + AO_WB, arena + AO_BB, arena + AO_WG,
                                     arena + AO_BG, v, vb, bovn, beta, gamma);
    k_mn<<<64, 256, 0, stream>>>(arena + AO_MEM, invmn);
    k_sim<<<2048, 256, 0, stream>>>(vb, arena + AO_MEM, bovn, invmn, beta, E, S);
    k_conv<<<2048, 256, 0, stream>>>(E, AT, S, gamma, arena + AO_CK, arena + AO_CB, T);
    k_vp2<<<320, 256, 0, stream>>>(v, T, vpb);
    k_add<<<256, 256, 0, stream>>>(AT, vpb, arena + AO_MEM, m2T);
    k_read<<<1024, 256, 0, stream>>>(arena + AO_X, WpT, arena + AO_BP, m2T, outacc, Sp);
    k_out<<<256, 256, 0, stream>>>(outacc, Sp, outp);
}